// Round 4
// baseline (26465.659 us; speedup 1.0000x reference)
//
#include <hip/hip_runtime.h>
#include <math.h>

#define TT 1024
#define DD 512

typedef unsigned int u32;
typedef unsigned long long u64;
typedef _Float16 half2_t __attribute__((ext_vector_type(2)));

// ---------------- tagged cross-block atomics (agent scope, relaxed; NO fences) ----
static __device__ __forceinline__ u64 aload64(const u64* p) {
    return __hip_atomic_load(p, __ATOMIC_RELAXED, __HIP_MEMORY_SCOPE_AGENT);
}
static __device__ __forceinline__ void astore64(u64* p, u64 v) {
    __hip_atomic_store(p, v, __ATOMIC_RELAXED, __HIP_MEMORY_SCOPE_AGENT);
}
static __device__ __forceinline__ u64 packf(float v, u32 tag) {
    union { float f; u32 u; } c; c.f = v; return ((u64)tag << 32) | (u64)c.u;
}
static __device__ __forceinline__ float unpackf(u64 w) {
    union { u32 u; float f; } c; c.u = (u32)w; return c.f;
}
static __device__ __forceinline__ u64 packu(u32 v, u32 tag) { return ((u64)tag << 32) | (u64)v; }

static __device__ __forceinline__ float redux8(float v) {
    v += __shfl_xor(v, 1); v += __shfl_xor(v, 2); v += __shfl_xor(v, 4); return v;
}
static __device__ __forceinline__ float sum64(float v) {
    #pragma unroll
    for (int o = 32; o > 0; o >>= 1) v += __shfl_xor(v, o);
    return v;
}
static __device__ __forceinline__ float expc(float x) { return __expf(fminf(x, 60.f)); }
static __device__ __forceinline__ float fast_tanh(float x) {
    float xc = fminf(fmaxf(x, -15.f), 15.f);
    float e = __expf(2.f * xc);
    return (e - 1.f) / (e + 1.f);
}
static __device__ __forceinline__ float fdot2_(u32 a, u32 b, float c) {
#if __has_builtin(__builtin_amdgcn_fdot2)
    return __builtin_amdgcn_fdot2(__builtin_bit_cast(half2_t, a),
                                  __builtin_bit_cast(half2_t, b), c, false);
#else
    half2_t ah = __builtin_bit_cast(half2_t, a), bh = __builtin_bit_cast(half2_t, b);
    return c + (float)ah.x * (float)bh.x + (float)ah.y * (float)bh.y;
#endif
}

// ---------------- projection GEMM (unchanged) ----------------
__global__ __launch_bounds__(256) void proj_kernel(const float* __restrict__ x,
                                                   const float* __restrict__ Wxz,
                                                   float* __restrict__ xp,
                                                   float* __restrict__ z) {
    __shared__ float As[16][66];
    __shared__ float Bs[16][66];
    const int m0 = blockIdx.x * 64;
    const int n0 = blockIdx.y * 64;
    const int tid = threadIdx.x;
    const int tm = tid / 16, tn = tid % 16;
    float c[4][4] = {};
    for (int k0 = 0; k0 < 512; k0 += 16) {
        const int r = tid >> 2, c4 = (tid & 3) * 4;
        float4 a4 = *(const float4*)(x + (size_t)(m0 + r) * 512 + k0 + c4);
        float4 b4 = *(const float4*)(Wxz + (size_t)(n0 + r) * 512 + k0 + c4);
        As[c4 + 0][r] = a4.x; As[c4 + 1][r] = a4.y; As[c4 + 2][r] = a4.z; As[c4 + 3][r] = a4.w;
        Bs[c4 + 0][r] = b4.x; Bs[c4 + 1][r] = b4.y; Bs[c4 + 2][r] = b4.z; Bs[c4 + 3][r] = b4.w;
        __syncthreads();
        #pragma unroll
        for (int k = 0; k < 16; ++k) {
            float a0 = As[k][tm * 4 + 0], a1 = As[k][tm * 4 + 1];
            float a2 = As[k][tm * 4 + 2], a3 = As[k][tm * 4 + 3];
            float b0 = Bs[k][tn * 4 + 0], b1 = Bs[k][tn * 4 + 1];
            float b2 = Bs[k][tn * 4 + 2], b3 = Bs[k][tn * 4 + 3];
            c[0][0] += a0 * b0; c[0][1] += a0 * b1; c[0][2] += a0 * b2; c[0][3] += a0 * b3;
            c[1][0] += a1 * b0; c[1][1] += a1 * b1; c[1][2] += a1 * b2; c[1][3] += a1 * b3;
            c[2][0] += a2 * b0; c[2][1] += a2 * b1; c[2][2] += a2 * b2; c[2][3] += a2 * b3;
            c[3][0] += a3 * b0; c[3][1] += a3 * b1; c[3][2] += a3 * b2; c[3][3] += a3 * b3;
        }
        __syncthreads();
    }
    #pragma unroll
    for (int i = 0; i < 4; ++i) {
        const int m = m0 + tm * 4 + i;
        #pragma unroll
        for (int j = 0; j < 4; ++j) {
            const int e = n0 + tn * 4 + j;
            if (e < 512) xp[(size_t)m * 512 + e] = c[i][j];
            else         z[(size_t)m * 512 + (e - 512)] = c[i][j];
        }
    }
}

// ---------------- recurrence: 64 blocks = 8 batches x 8 slices, dual-sliced tape ----
// Cross-block per step: SYNC-H (h as 256 tagged u64 f16-pairs) + SYNC-S (16 scalars/block).
// Everything else local: scores on n-slice tape, rv on d-slice tape, redundant wv matvec.
__global__ __launch_bounds__(512) void rec_kernel(
    const float* __restrict__ tape0, const float* __restrict__ hwork0,
    const float* __restrict__ W_h, const float* __restrict__ b_h,
    const float* __restrict__ W_write,
    const float* __restrict__ g_z, const float* __restrict__ g_r,
    const float* __restrict__ g_h, const float* __restrict__ b_gate,
    const float* __restrict__ Zbuf,
    float* __restrict__ out, float* __restrict__ tape_out,
    u64* hbuf, u64* q0buf, u64* ewbuf) {
    const int b = blockIdx.x & 7, s = blockIdx.x >> 3;
    const int tid = threadIdx.x, lane = tid & 63, wid = tid >> 6;
    const int l = tid & 7, rw = tid >> 3;   // k-octant, row-in-64-group
    const int d0 = s * 64;
    const float scale = 0.044194173824159216f;  // 1/sqrt(512)

    __shared__ __attribute__((aligned(16))) float tpn[8][DD];     // local n rows, all d
    __shared__ __attribute__((aligned(16))) float tpd[64 * 64];   // all n, local d chunk (flat, pitch 64)
    __shared__ __attribute__((aligned(16))) float hf[DD];         // h(t) fp32
    __shared__ __attribute__((aligned(16))) u32  h2s[8][36];      // h f16-pairs, swizzled rows
    __shared__ __attribute__((aligned(16))) float wvs[DD];        // wv(t) full
    __shared__ __attribute__((aligned(16))) float red[8][64];
    __shared__ __attribute__((aligned(16))) float rvc[64];
    __shared__ __attribute__((aligned(16))) float hhc[64];
    __shared__ __attribute__((aligned(16))) float hnc[64];
    __shared__ __attribute__((aligned(16))) float xpc[64];
    __shared__ __attribute__((aligned(16))) float zc[64];
    __shared__ __attribute__((aligned(16))) float bhc[64];
    __shared__ __attribute__((aligned(16))) float a_l[64];
    __shared__ __attribute__((aligned(16))) float c1_l[64];
    __shared__ float qs[8];
    __shared__ float c2_s, qv_s;

    // --- resident f16 weights: W_write full (8 passes x 64 rows), W_h d-chunk ---
    u32 ww[8][32];   // pass p: row p*64+rw, cols [l*64, l*64+64) as 32 f16-pairs
    u32 wh[32];      // row d0+rw, cols [l*64, l*64+64)
    #pragma unroll
    for (int p = 0; p < 8; ++p) {
        const float4* src = (const float4*)(W_write + (size_t)(p * 64 + rw) * DD + l * 64);
        #pragma unroll
        for (int j = 0; j < 16; ++j) {
            float4 v = src[j];
            ww[p][2 * j]     = __builtin_bit_cast(u32, __builtin_amdgcn_cvt_pkrtz(v.x, v.y));
            ww[p][2 * j + 1] = __builtin_bit_cast(u32, __builtin_amdgcn_cvt_pkrtz(v.z, v.w));
        }
    }
    {
        const float4* src = (const float4*)(W_h + (size_t)(d0 + rw) * DD + l * 64);
        #pragma unroll
        for (int j = 0; j < 16; ++j) {
            float4 v = src[j];
            wh[2 * j]     = __builtin_bit_cast(u32, __builtin_amdgcn_cvt_pkrtz(v.x, v.y));
            wh[2 * j + 1] = __builtin_bit_cast(u32, __builtin_amdgcn_cvt_pkrtz(v.z, v.w));
        }
    }
    const int de = (tid >= 64 && tid < 128) ? lane : 0;
    const float gzr = g_z[d0 + de], grr = g_r[d0 + de], ghr = g_h[d0 + de], bgr = b_gate[d0 + de];

    // --- init LDS ---
    {   // tpn: wave wid = local row
        const float4* src = (const float4*)(tape0 + ((size_t)(b * 64 + s * 8 + wid)) * DD);
        ((float4*)&tpn[wid][0])[lane]   = src[lane];
        ((float4*)&tpn[wid][256])[lane] = src[64 + lane];
    }
    {   // tpd: flat 8 elems per thread: n = tid>>3, dd = (tid&7)*8
        const float4* src = (const float4*)(tape0 + ((size_t)(b * 64 + (tid >> 3))) * DD + d0 + (tid & 7) * 8);
        ((float4*)&tpd[tid * 8])[0] = src[0];
        ((float4*)&tpd[tid * 8])[1] = src[1];
    }
    if (tid < 128) ((float4*)hf)[tid] = ((const float4*)(hwork0 + (size_t)b * DD))[tid];
    if (tid < 64) bhc[tid] = b_h[d0 + tid];
    wvs[tid] = 0.f;
    if (tid >= 384 && tid < 448) xpc[tid - 384] = out[((size_t)(b * TT)) * DD + d0 + (tid - 384)];
    else if (tid >= 448)         zc[tid - 448] = Zbuf[((size_t)(b * TT)) * DD + d0 + (tid - 448)];
    if (tid == 0) { qv_s = 0.f; c2_s = 0.f; }
    __syncthreads();
    // pack h2s from hf
    if (tid < 256) {
        u32 pr = __builtin_bit_cast(u32, __builtin_amdgcn_cvt_pkrtz(hf[2 * tid], hf[2 * tid + 1]));
        h2s[tid >> 5][tid & 31] = pr;
    }
    __syncthreads();
    // init hh = (W_h . h(-1))[d-chunk]  and  publish q0(n,0) = h(-1).tape_init(n)  (tag 1, parity 1)
    {
        u32 hreg[32];
        #pragma unroll
        for (int j = 0; j < 8; ++j) {
            uint4 v = ((const uint4*)&h2s[l][0])[j];
            hreg[4 * j] = v.x; hreg[4 * j + 1] = v.y; hreg[4 * j + 2] = v.z; hreg[4 * j + 3] = v.w;
        }
        float acc = 0.f;
        #pragma unroll
        for (int j = 0; j < 32; ++j) acc = fdot2_(wh[j], hreg[j], acc);
        acc = redux8(acc);
        if (l == 0) hhc[rw] = acc;
    }
    {
        float4 tv0 = ((const float4*)&tpn[wid][0])[lane];
        float4 hv0 = ((const float4*)&hf[0])[lane];
        float4 tv1 = ((const float4*)&tpn[wid][256])[lane];
        float4 hv1 = ((const float4*)&hf[256])[lane];
        float acc = tv0.x * hv0.x + tv0.y * hv0.y + tv0.z * hv0.z + tv0.w * hv0.w
                  + tv1.x * hv1.x + tv1.y * hv1.y + tv1.z * hv1.z + tv1.w * hv1.w;
        acc = sum64(acc);
        if (lane == 0) astore64(&q0buf[(1 * 8 + b) * 64 + s * 8 + wid], packf(acc, 1u));
    }
    __syncthreads();

    // ---------------- main scan ----------------
    for (int t = 0; t < TT; ++t) {
        const int parH = t & 1;
        const int parS = t & 1;            // E/G publish parity (consumed at A(t+1))
        const int parA = (t + 1) & 1;      // A reads (t-1)'s parity
        const u32 tagA = (u32)(t + 1);
        const u32 tagH = (u32)(t + 1);

        // ---- A: poll SYNC-S, softmaxes (wave0) ----
        if (wid == 0) {
            if (t == 0) {
                u64 q;
                do { q = aload64(&q0buf[(parA * 8 + b) * 64 + lane]); } while ((u32)(q >> 32) != tagA);
                float er = expc(scale * unpackf(q));
                float Zr = sum64(er);
                float r = __fdividef(er, Zr);
                a_l[lane] = 0.f; c1_l[lane] = r;
                if (lane == 0) c2_s = 0.f;
            } else {
                u64 qe, qq;
                do {
                    qe = aload64(&ewbuf[(parA * 8 + b) * 64 + lane]);
                    qq = aload64(&q0buf[(parA * 8 + b) * 64 + lane]);
                } while ((u32)(qe >> 32) != tagA || (u32)(qq >> 32) != tagA);
                float qv = sum64((lane < 8) ? qs[lane] : 0.f);   // qv = h(t-1).wv(t-1)
                float ew = unpackf(qe), q0 = unpackf(qq);
                float Zw = sum64(ew);
                float a = __fdividef(ew, Zw);
                float er = expc(scale * ((1.f - a) * q0 + a * qv));
                float Zr = sum64(er);
                float r = __fdividef(er, Zr);
                a_l[lane] = a; c1_l[lane] = r * (1.f - a);
                float c2 = sum64(r * a);
                if (lane == 0) c2_s = c2;
            }
        }
        __syncthreads();
        // ---- B1: rv partials over OLD tpd (state t-2), c1-weighted ----
        {
            float acc = 0.f;
            #pragma unroll
            for (int i = 0; i < 8; ++i) acc += c1_l[wid * 8 + i] * tpd[(wid * 8 + i) * 64 + lane];
            red[wid][lane] = acc;
        }
        __syncthreads();
        // ---- B2: rv combine (wave0) ----
        if (tid < 64) {
            float acc = c2_s * wvs[d0 + tid];
            #pragma unroll
            for (int g = 0; g < 8; ++g) acc += red[g][tid];
            rvc[tid] = acc;
        }
        __syncthreads();
        // ---- B3: tape updates (state t-2 -> t-1, a = a(t-1)); wave0 also computes h(t) ----
        {
            const float an = a_l[tid >> 3];
            const float4* wsrc = (const float4*)&wvs[d0 + (tid & 7) * 8];
            #pragma unroll
            for (int hh = 0; hh < 2; ++hh) {
                float4 tp = ((float4*)&tpd[tid * 8])[hh];
                float4 w4 = wsrc[hh];
                tp.x += an * (w4.x - tp.x); tp.y += an * (w4.y - tp.y);
                tp.z += an * (w4.z - tp.z); tp.w += an * (w4.w - tp.w);
                ((float4*)&tpd[tid * 8])[hh] = tp;
            }
            const float an2 = a_l[s * 8 + wid];
            float4 t0 = ((float4*)&tpn[wid][0])[lane];
            float4 w0 = ((const float4*)&wvs[0])[lane];
            t0.x += an2 * (w0.x - t0.x); t0.y += an2 * (w0.y - t0.y);
            t0.z += an2 * (w0.z - t0.z); t0.w += an2 * (w0.w - t0.w);
            ((float4*)&tpn[wid][0])[lane] = t0;
            float4 t1 = ((float4*)&tpn[wid][256])[lane];
            float4 w1 = ((const float4*)&wvs[256])[lane];
            t1.x += an2 * (w1.x - t1.x); t1.y += an2 * (w1.y - t1.y);
            t1.z += an2 * (w1.z - t1.z); t1.w += an2 * (w1.w - t1.w);
            ((float4*)&tpn[wid][256])[lane] = t1;
        }
        if (tid < 64) {
            float hn = fast_tanh(xpc[lane] + hhc[lane] + rvc[lane] + bhc[lane]);
            hnc[lane] = hn;
        }
        __syncthreads();
        // ---- C: publish h(t) pairs (wave0) + out epilogue (wave1) ----
        if (tid < 64) {
            float hn = hnc[lane];
            float ho = __shfl_xor(hn, 1);
            if ((lane & 1) == 0) {
                u32 pr = __builtin_bit_cast(u32, __builtin_amdgcn_cvt_pkrtz(hn, ho));
                astore64(&hbuf[((size_t)parH * 8 + b) * 256 + (d0 >> 1) + (lane >> 1)], packu(pr, tagH));
            }
        } else if (tid < 128) {
            float h = hnc[lane];
            float g = zc[lane] * gzr + rvc[lane] * grr + h * ghr + bgr;
            g = fminf(fmaxf(g, -20.f), 20.f);
            float sig = 1.f / (1.f + __expf(-g));
            out[((size_t)(b * TT + t)) * DD + d0 + lane] = h * g * sig;
        }
        __syncthreads();
        // ---- D: poll-gather full h(t) (f16 pairs) + prefetch xp/z(t+1) ----
        if (tid < 256) {
            u64 v;
            do { v = aload64(&hbuf[((size_t)parH * 8 + b) * 256 + tid]); } while ((u32)(v >> 32) != tagH);
            u32 pr = (u32)v;
            h2s[tid >> 5][tid & 31] = pr;
            half2_t hp = __builtin_bit_cast(half2_t, pr);
            hf[2 * tid] = (float)hp.x;
            hf[2 * tid + 1] = (float)hp.y;
        } else if (tid < 320) {
            const int tn = (t + 1 < TT) ? t + 1 : t;
            xpc[tid - 256] = out[((size_t)(b * TT + tn)) * DD + d0 + (tid - 256)];
        } else if (tid < 384) {
            const int tn = (t + 1 < TT) ? t + 1 : t;
            zc[tid - 320] = Zbuf[((size_t)(b * TT + tn)) * DD + d0 + (tid - 320)];
        }
        __syncthreads();
        // ---- E: publish q0'(n) = h(t).tpn(state t-1) early ----
        {
            float4 tv0 = ((const float4*)&tpn[wid][0])[lane];
            float4 hv0 = ((const float4*)&hf[0])[lane];
            float4 tv1 = ((const float4*)&tpn[wid][256])[lane];
            float4 hv1 = ((const float4*)&hf[256])[lane];
            float acc = tv0.x * hv0.x + tv0.y * hv0.y + tv0.z * hv0.z + tv0.w * hv0.w
                      + tv1.x * hv1.x + tv1.y * hv1.y + tv1.z * hv1.z + tv1.w * hv1.w;
            acc = sum64(acc);
            if (lane == 0) astore64(&q0buf[(parS * 8 + b) * 64 + s * 8 + wid], packf(acc, (u32)(t + 2)));
        }
        // ---- F: wv(t) = W_write . h(t)  (redundant full matvec, fdot2) ----
        u32 hreg[32];
        {
            #pragma unroll
            for (int j = 0; j < 8; ++j) {
                uint4 v = ((const uint4*)&h2s[l][0])[j];
                hreg[4 * j] = v.x; hreg[4 * j + 1] = v.y; hreg[4 * j + 2] = v.z; hreg[4 * j + 3] = v.w;
            }
            #pragma unroll
            for (int p = 0; p < 8; ++p) {
                float acc = 0.f;
                #pragma unroll
                for (int j = 0; j < 32; ++j) acc = fdot2_(ww[p][j], hreg[j], acc);
                acc = redux8(acc);
                if (l == 0) wvs[p * 64 + rw] = acc;
            }
        }
        __syncthreads();
        // ---- G: e_w publish, hh' chunk, qv partials ----
        {
            float4 tv0 = ((const float4*)&tpn[wid][0])[lane];
            float4 wv0 = ((const float4*)&wvs[0])[lane];
            float4 tv1 = ((const float4*)&tpn[wid][256])[lane];
            float4 wv1 = ((const float4*)&wvs[256])[lane];
            float acc = tv0.x * wv0.x + tv0.y * wv0.y + tv0.z * wv0.z + tv0.w * wv0.w
                      + tv1.x * wv1.x + tv1.y * wv1.y + tv1.z * wv1.z + tv1.w * wv1.w;
            acc = sum64(acc);
            if (lane == 0) astore64(&ewbuf[(parS * 8 + b) * 64 + s * 8 + wid],
                                    packf(expc(scale * acc), (u32)(t + 2)));
        }
        {
            float acc = 0.f;
            #pragma unroll
            for (int j = 0; j < 32; ++j) acc = fdot2_(wh[j], hreg[j], acc);
            acc = redux8(acc);
            if (l == 0) hhc[rw] = acc;
        }
        {
            float p = hf[tid < 512 ? tid : 0] * wvs[tid < 512 ? tid : 0];
            p = sum64(p);
            if (lane == 0) qs[wid] = p;
        }
        __syncthreads();
    }

    // ---- extra-A: final tape update (a(T-1)) + write tape_final ----
    {
        const int parA = (TT + 1) & 1;
        const u32 tagA = (u32)(TT + 1);
        if (wid == 0) {
            u64 qe;
            do { qe = aload64(&ewbuf[(parA * 8 + b) * 64 + lane]); } while ((u32)(qe >> 32) != tagA);
            float ew = unpackf(qe);
            float Zw = sum64(ew);
            a_l[lane] = __fdividef(ew, Zw);
        }
        __syncthreads();
        const float an = a_l[s * 8 + wid];
        float* dst = tape_out + ((size_t)(b * 64 + s * 8 + wid)) * DD;
        float4 t0 = ((float4*)&tpn[wid][0])[lane];
        float4 w0 = ((const float4*)&wvs[0])[lane];
        t0.x += an * (w0.x - t0.x); t0.y += an * (w0.y - t0.y);
        t0.z += an * (w0.z - t0.z); t0.w += an * (w0.w - t0.w);
        ((float4*)dst)[lane] = t0;
        float4 t1 = ((float4*)&tpn[wid][256])[lane];
        float4 w1 = ((const float4*)&wvs[256])[lane];
        t1.x += an * (w1.x - t1.x); t1.y += an * (w1.y - t1.y);
        t1.z += an * (w1.z - t1.z); t1.w += an * (w1.w - t1.w);
        ((float4*)dst)[64 + lane] = t1;
    }
}

extern "C" void kernel_launch(void* const* d_in, const int* in_sizes, int n_in,
                              void* d_out, int out_size, void* d_ws, size_t ws_size,
                              hipStream_t stream) {
    const float* x       = (const float*)d_in[0];   // [8,1024,512]
    const float* tape0   = (const float*)d_in[1];   // [8,64,512]
    const float* hwork0  = (const float*)d_in[2];   // [8,512]
    const float* W_h     = (const float*)d_in[3];   // [512,512]
    const float* W_xz    = (const float*)d_in[4];   // [1024,512]
    const float* b_h     = (const float*)d_in[5];   // [512]
    const float* W_write = (const float*)d_in[6];   // [512,512]
    const float* g_z     = (const float*)d_in[7];
    const float* g_r     = (const float*)d_in[8];
    const float* g_h     = (const float*)d_in[9];
    const float* b_gate  = (const float*)d_in[10];

    float* out  = (float*)d_out;                        // outs [8,1024,512]
    float* tout = out + (size_t)8 * TT * DD;            // tape_final [8,64,512]

    char* ws = (char*)d_ws;
    u64* hbuf  = (u64*)ws;                              // [2][8][256] = 32 KB
    u64* q0buf = (u64*)(ws + 32768);                    // [2][8][64]  = 8 KB
    u64* ewbuf = (u64*)(ws + 40960);                    // [2][8][64]  = 8 KB
    float* Zbuf = (float*)(ws + 65536);                 // 16 MB

    (void)in_sizes; (void)n_in; (void)out_size; (void)ws_size;

    // tags are equality-checked against monotone values; 0xAA poison never matches.
    dim3 pgrid(128, 16);
    proj_kernel<<<pgrid, 256, 0, stream>>>(x, W_xz, out, Zbuf);
    rec_kernel<<<64, 512, 0, stream>>>(tape0, hwork0, W_h, b_h, W_write,
                                       g_z, g_r, g_h, b_gate, Zbuf,
                                       out, tout, hbuf, q0buf, ewbuf);
}

// Round 5
// 10355.376 us; speedup vs baseline: 2.5557x; 2.5557x over previous
//
#include <hip/hip_runtime.h>
#include <math.h>

#define TT 1024
#define DD 512
#define PITCH 516   // tape row pitch in floats (132 KB total); 4-float skew per row

typedef unsigned int u32;
typedef unsigned long long u64;
typedef _Float16 half2_t __attribute__((ext_vector_type(2)));

// ---------------- tagged cross-block atomics (agent scope, relaxed; R2-proven) ----
static __device__ __forceinline__ u64 aload64(const u64* p) {
    return __hip_atomic_load(p, __ATOMIC_RELAXED, __HIP_MEMORY_SCOPE_AGENT);
}
static __device__ __forceinline__ void astore64(u64* p, u64 v) {
    __hip_atomic_store(p, v, __ATOMIC_RELAXED, __HIP_MEMORY_SCOPE_AGENT);
}
static __device__ __forceinline__ u32 pkh2(float lo, float hi) {
    return __builtin_bit_cast(u32, __builtin_amdgcn_cvt_pkrtz(lo, hi));
}
static __device__ __forceinline__ float2 uph2(u32 v) {
    half2_t h = __builtin_bit_cast(half2_t, v);
    return make_float2((float)h.x, (float)h.y);
}

static __device__ __forceinline__ float redux8(float v) {
    v += __shfl_xor(v, 1); v += __shfl_xor(v, 2); v += __shfl_xor(v, 4); return v;
}
static __device__ __forceinline__ float sum64(float v) {
    #pragma unroll
    for (int o = 32; o > 0; o >>= 1) v += __shfl_xor(v, o);
    return v;
}
static __device__ __forceinline__ float expc(float x) { return __expf(fminf(x, 60.f)); }
static __device__ __forceinline__ float fast_tanh(float x) {
    float xc = fminf(fmaxf(x, -15.f), 15.f);
    float e = __expf(2.f * xc);
    return (e - 1.f) / (e + 1.f);
}

// dot of 64 resident fp32 weights (16 float4) with 64 LDS floats
static __device__ __forceinline__ float dot64(const float4 (&w)[16], const float* hr) {
    float a0 = 0.f, a1 = 0.f, a2 = 0.f, a3 = 0.f;
    #pragma unroll
    for (int j = 0; j < 16; j += 4) {
        float4 h0 = *(const float4*)(hr + 4 * (j + 0));
        float4 h1 = *(const float4*)(hr + 4 * (j + 1));
        float4 h2 = *(const float4*)(hr + 4 * (j + 2));
        float4 h3 = *(const float4*)(hr + 4 * (j + 3));
        a0 += w[j + 0].x * h0.x + w[j + 0].y * h0.y + w[j + 0].z * h0.z + w[j + 0].w * h0.w;
        a1 += w[j + 1].x * h1.x + w[j + 1].y * h1.y + w[j + 1].z * h1.z + w[j + 1].w * h1.w;
        a2 += w[j + 2].x * h2.x + w[j + 2].y * h2.y + w[j + 2].z * h2.z + w[j + 2].w * h2.w;
        a3 += w[j + 3].x * h3.x + w[j + 3].y * h3.y + w[j + 3].z * h3.z + w[j + 3].w * h3.w;
    }
    return (a0 + a1) + (a2 + a3);
}

// ---------------- projection GEMM (unchanged) ----------------
__global__ __launch_bounds__(256) void proj_kernel(const float* __restrict__ x,
                                                   const float* __restrict__ Wxz,
                                                   float* __restrict__ xp,
                                                   float* __restrict__ z) {
    __shared__ float As[16][66];
    __shared__ float Bs[16][66];
    const int m0 = blockIdx.x * 64;
    const int n0 = blockIdx.y * 64;
    const int tid = threadIdx.x;
    const int tm = tid / 16, tn = tid % 16;
    float c[4][4] = {};
    for (int k0 = 0; k0 < 512; k0 += 16) {
        const int r = tid >> 2, c4 = (tid & 3) * 4;
        float4 a4 = *(const float4*)(x + (size_t)(m0 + r) * 512 + k0 + c4);
        float4 b4 = *(const float4*)(Wxz + (size_t)(n0 + r) * 512 + k0 + c4);
        As[c4 + 0][r] = a4.x; As[c4 + 1][r] = a4.y; As[c4 + 2][r] = a4.z; As[c4 + 3][r] = a4.w;
        Bs[c4 + 0][r] = b4.x; Bs[c4 + 1][r] = b4.y; Bs[c4 + 2][r] = b4.z; Bs[c4 + 3][r] = b4.w;
        __syncthreads();
        #pragma unroll
        for (int k = 0; k < 16; ++k) {
            float a0 = As[k][tm * 4 + 0], a1 = As[k][tm * 4 + 1];
            float a2 = As[k][tm * 4 + 2], a3 = As[k][tm * 4 + 3];
            float b0 = Bs[k][tn * 4 + 0], b1 = Bs[k][tn * 4 + 1];
            float b2 = Bs[k][tn * 4 + 2], b3 = Bs[k][tn * 4 + 3];
            c[0][0] += a0 * b0; c[0][1] += a0 * b1; c[0][2] += a0 * b2; c[0][3] += a0 * b3;
            c[1][0] += a1 * b0; c[1][1] += a1 * b1; c[1][2] += a1 * b2; c[1][3] += a1 * b3;
            c[2][0] += a2 * b0; c[2][1] += a2 * b1; c[2][2] += a2 * b2; c[2][3] += a2 * b3;
            c[3][0] += a3 * b0; c[3][1] += a3 * b1; c[3][2] += a3 * b2; c[3][3] += a3 * b3;
        }
        __syncthreads();
    }
    #pragma unroll
    for (int i = 0; i < 4; ++i) {
        const int m = m0 + tm * 4 + i;
        #pragma unroll
        for (int j = 0; j < 4; ++j) {
            const int e = n0 + tn * 4 + j;
            if (e < 512) xp[(size_t)m * 512 + e] = c[i][j];
            else         z[(size_t)m * 512 + (e - 512)] = c[i][j];
        }
    }
}

// ---------------- recurrence: 64 blocks = 8 batches x 8 d-slices ----------------
// ONE cross-block sync per step. Every block holds the FULL tape (fp32, dyn LDS)
// and updates it identically from identically-gathered (f16) h and wv=sum c_j.
// Publish per block per step: h-slice (32 u64) + c_j = W_write[:,slice]*h_slice
// (256 u64), tagged f16-pairs, double-buffered by parity. Polls use s_sleep backoff.
__global__ __launch_bounds__(512) void rec_kernel(
    const float* __restrict__ tape0, const float* __restrict__ hwork0,
    const float* __restrict__ W_h, const float* __restrict__ b_h,
    const float* __restrict__ W_write,
    const float* __restrict__ g_z, const float* __restrict__ g_r,
    const float* __restrict__ g_h, const float* __restrict__ b_gate,
    const float* __restrict__ Zbuf,
    float* __restrict__ out, float* __restrict__ tape_out,
    u64* hbuf, u64* cbuf) {
    extern __shared__ float smem[];
    float* tape = smem;                       // 64*PITCH = 33024
    float* hf   = smem + 64 * PITCH;          // 512
    float* wvs  = hf + 512;                   // 512
    float* rvc  = wvs + 512;                  // 512
    float* hn_s = rvc + 512;                  // 64
    float* hh_s = hn_s + 64;                  // 64
    float* ws_s = hh_s + 64;                  // 64
    float* q0_s = ws_s + 64;                  // 64
    float2* ac_s = (float2*)(q0_s + 64);      // 64 float2 (a, c1)
    float* xpc  = (float*)(ac_s + 64);        // 64
    float* zc   = xpc + 64;                   // 64
    float* misc = zc + 64;                    // [0]=qv, [1]=c2

    const int b = blockIdx.x & 7, s = blockIdx.x >> 3;
    const int tid = threadIdx.x, lane = tid & 63, wid = tid >> 6;
    const int r8 = tid >> 3, l = tid & 7;
    const int d0 = s * 64;
    const float scale = 0.044194173824159216f;  // 1/sqrt(512)

    // --- resident weights ---
    float4 wh[16];    // W_h[d0+r8][l*64 + 4j .. +3]
    float4 wwc[16];   // W_write[tid][d0 + 4j .. +3]  (column slice for c_j)
    {
        const float4* w1 = (const float4*)(W_h + (size_t)(d0 + r8) * DD + l * 64);
        #pragma unroll
        for (int j = 0; j < 16; ++j) wh[j] = w1[j];
        const float4* w2 = (const float4*)(W_write + (size_t)tid * DD + d0);
        #pragma unroll
        for (int j = 0; j < 16; ++j) wwc[j] = w2[j];
    }
    float gz = 0.f, gr = 0.f, gh = 0.f, bg = 0.f, bhr = 0.f;
    if (wid == 0) bhr = b_h[d0 + lane];
    if (wid == 1) { gz = g_z[d0 + lane]; gr = g_r[d0 + lane]; gh = g_h[d0 + lane]; bg = b_gate[d0 + lane]; }

    // --- tape init: full tape into LDS (wave wid loads rows 8wid..8wid+7) ---
    #pragma unroll
    for (int rr = 0; rr < 8; ++rr) {
        const int n = 8 * wid + rr;
        const float4* src = (const float4*)(tape0 + ((size_t)(b * 64 + n)) * DD);
        float4 t0 = src[lane * 2], t1 = src[lane * 2 + 1];
        *(float4*)(tape + n * PITCH + lane * 8) = t0;
        *(float4*)(tape + n * PITCH + lane * 8 + 4) = t1;
    }

    // ---------------- main scan: ONE sync per step ----------------
    for (int t = 0; t < TT; ++t) {
        // phase0: issue xp/z global loads into regs (latency hidden behind poll)
        float xpr = 0.f, zr = 0.f;
        if (wid == 2)      xpr = out[((size_t)(b * TT + t)) * DD + d0 + lane];
        else if (wid == 3) zr  = Zbuf[((size_t)(b * TT + t)) * DD + d0 + lane];

        // phase1: gather h(t-1) + wv(t-1)   (t=0: from hwork0, wv=0; no poll)
        if (t == 0) {
            if (tid < 128) ((float4*)hf)[tid] = ((const float4*)(hwork0 + (size_t)b * DD))[tid];
            wvs[tid] = 0.f;
        } else {
            const int par = t & 1;
            const u32 tg = (u32)t;
            if (tid < 256) {
                const u64* base = cbuf + ((size_t)(par * 8 + b) * 8) * 256 + tid;
                u64 v[8];
                for (;;) {
                    bool ok = true;
                    #pragma unroll
                    for (int j = 0; j < 8; ++j) v[j] = aload64(base + j * 256);
                    #pragma unroll
                    for (int j = 0; j < 8; ++j) ok = ok && ((u32)(v[j] >> 32) == tg);
                    if (ok) break;
                    __builtin_amdgcn_s_sleep(2);
                }
                float a0 = 0.f, a1 = 0.f;
                #pragma unroll
                for (int j = 0; j < 8; ++j) { float2 p = uph2((u32)v[j]); a0 += p.x; a1 += p.y; }
                wvs[2 * tid] = a0; wvs[2 * tid + 1] = a1;
            } else {
                const int k = tid - 256;
                const u64* p = hbuf + (size_t)(par * 8 + b) * 256 + k;
                u64 v;
                for (;;) {
                    v = aload64(p);
                    if ((u32)(v >> 32) == tg) break;
                    __builtin_amdgcn_s_sleep(2);
                }
                float2 hp = uph2((u32)v);
                hf[2 * k] = hp.x; hf[2 * k + 1] = hp.y;
            }
        }
        __syncthreads();

        // phase2: hh slice (all), qv (wave0), sweep1: ws(n)=wv.tape_old(n), q0(n)=h.tape_old(n)
        {
            float acc = dot64(wh, hf + l * 64);
            acc = redux8(acc);
            if (l == 0) hh_s[r8] = acc;
        }
        if (wid == 0) {
            float q = 0.f;
            #pragma unroll
            for (int i = 0; i < 8; ++i) q += hf[lane * 8 + i] * wvs[lane * 8 + i];
            q = sum64(q);
            if (lane == 0) misc[0] = q;
        }
        {
            float4 wa = ((const float4*)wvs)[lane * 2], wb = ((const float4*)wvs)[lane * 2 + 1];
            float4 ha = ((const float4*)hf)[lane * 2],  hb2 = ((const float4*)hf)[lane * 2 + 1];
            #pragma unroll
            for (int rr = 0; rr < 8; ++rr) {
                const int n = 8 * wid + rr;
                const float4 t0 = *(const float4*)(tape + n * PITCH + lane * 8);
                const float4 t1 = *(const float4*)(tape + n * PITCH + lane * 8 + 4);
                float pw = t0.x * wa.x + t0.y * wa.y + t0.z * wa.z + t0.w * wa.w
                         + t1.x * wb.x + t1.y * wb.y + t1.z * wb.z + t1.w * wb.w;
                float pq = t0.x * ha.x + t0.y * ha.y + t0.z * ha.z + t0.w * ha.w
                         + t1.x * hb2.x + t1.y * hb2.y + t1.z * hb2.z + t1.w * hb2.w;
                pw = sum64(pw); pq = sum64(pq);
                if (lane == 0) { ws_s[n] = pw; q0_s[n] = pq; }
            }
        }
        __syncthreads();

        // phase3: softmaxes (wave0); stash xp/z (waves 2,3)
        if (wid == 0) {
            float a = 0.f;
            if (t > 0) {
                float ew = expc(scale * ws_s[lane]);
                float Zw = sum64(ew);
                a = __fdividef(ew, Zw);
            }
            float sc = scale * ((1.f - a) * q0_s[lane] + a * misc[0]);
            float er = expc(sc);
            float Zr = sum64(er);
            float r_ = __fdividef(er, Zr);
            ac_s[lane] = make_float2(a, r_ * (1.f - a));
            float c2 = sum64(r_ * a);
            if (lane == 0) misc[1] = c2;
        } else if (wid == 2) xpc[lane] = xpr;
        else if (wid == 3)   zc[lane] = zr;
        __syncthreads();

        // phase4: column sweep — rv + tape lerp (conflict-free b32 column access)
        {
            const int d = tid;
            const float wvd = wvs[d];
            const float c2 = misc[1];
            float acc = 0.f;
            #pragma unroll 8
            for (int n = 0; n < 64; ++n) {
                float2 ac = ac_s[n];
                float tp = tape[n * PITCH + d];
                acc += ac.y * tp;
                tape[n * PITCH + d] = tp + ac.x * (wvd - tp);
            }
            rvc[d] = acc + c2 * wvd;
        }
        __syncthreads();

        // phase5: h(t) slice (wave0)
        if (wid == 0) hn_s[lane] = fast_tanh(xpc[lane] + hh_s[lane] + rvc[d0 + lane] + bhr);
        __syncthreads();

        // phase6: c_j column matvec + publish (tag t+1) + out epilogue (wave1)
        {
            float cj = 0.f;
            #pragma unroll
            for (int j = 0; j < 16; ++j) {
                float4 h4 = ((const float4*)hn_s)[j];
                cj += wwc[j].x * h4.x + wwc[j].y * h4.y + wwc[j].z * h4.z + wwc[j].w * h4.w;
            }
            float cn = __shfl_xor(cj, 1);
            const int par2 = (t + 1) & 1;
            const u32 tg = (u32)(t + 1);
            if ((tid & 1) == 0)
                astore64(cbuf + (((size_t)(par2 * 8 + b) * 8) + s) * 256 + (tid >> 1),
                         ((u64)tg << 32) | (u64)pkh2(cj, cn));
            if (tid < 32)
                astore64(hbuf + (size_t)(par2 * 8 + b) * 256 + s * 32 + tid,
                         ((u64)tg << 32) | (u64)pkh2(hn_s[2 * tid], hn_s[2 * tid + 1]));
            if (wid == 1) {
                float h = hn_s[lane];
                float g = zc[lane] * gz + rvc[d0 + lane] * gr + h * gh + bg;
                g = fminf(fmaxf(g, -20.f), 20.f);
                float sig = 1.f / (1.f + __expf(-g));
                out[((size_t)(b * TT + t)) * DD + d0 + lane] = h * g * sig;
            }
        }
        // no barrier needed: next phase1 touches only hf/wvs (not read here)
    }

    // ---------------- epilogue: final tape write-back ----------------
    {
        const int par = TT & 1;      // 0
        const u32 tg = (u32)TT;
        if (tid < 256) {             // gather wv(T-1) only
            const u64* base = cbuf + ((size_t)(par * 8 + b) * 8) * 256 + tid;
            u64 v[8];
            for (;;) {
                bool ok = true;
                #pragma unroll
                for (int j = 0; j < 8; ++j) v[j] = aload64(base + j * 256);
                #pragma unroll
                for (int j = 0; j < 8; ++j) ok = ok && ((u32)(v[j] >> 32) == tg);
                if (ok) break;
                __builtin_amdgcn_s_sleep(2);
            }
            float a0 = 0.f, a1 = 0.f;
            #pragma unroll
            for (int j = 0; j < 8; ++j) { float2 p = uph2((u32)v[j]); a0 += p.x; a1 += p.y; }
            wvs[2 * tid] = a0; wvs[2 * tid + 1] = a1;
        }
        __syncthreads();
        {   // ws sweep
            float4 wa = ((const float4*)wvs)[lane * 2], wb = ((const float4*)wvs)[lane * 2 + 1];
            #pragma unroll
            for (int rr = 0; rr < 8; ++rr) {
                const int n = 8 * wid + rr;
                const float4 t0 = *(const float4*)(tape + n * PITCH + lane * 8);
                const float4 t1 = *(const float4*)(tape + n * PITCH + lane * 8 + 4);
                float pw = t0.x * wa.x + t0.y * wa.y + t0.z * wa.z + t0.w * wa.w
                         + t1.x * wb.x + t1.y * wb.y + t1.z * wb.z + t1.w * wb.w;
                pw = sum64(pw);
                if (lane == 0) ws_s[n] = pw;
            }
        }
        __syncthreads();
        if (wid == 0) {
            float ew = expc(scale * ws_s[lane]);
            float Zw = sum64(ew);
            ac_s[lane] = make_float2(__fdividef(ew, Zw), 0.f);
        }
        __syncthreads();
        {   // final lerp
            const int d = tid;
            const float wvd = wvs[d];
            #pragma unroll 8
            for (int n = 0; n < 64; ++n) {
                float2 ac = ac_s[n];
                float tp = tape[n * PITCH + d];
                tape[n * PITCH + d] = tp + ac.x * (wvd - tp);
            }
        }
        __syncthreads();
        if (s == 0) {   // one slice per batch writes the (identical) tape
            #pragma unroll
            for (int rr = 0; rr < 8; ++rr) {
                const int n = 8 * wid + rr;
                float4 t0 = *(const float4*)(tape + n * PITCH + lane * 8);
                float4 t1 = *(const float4*)(tape + n * PITCH + lane * 8 + 4);
                float4* dst = (float4*)(tape_out + ((size_t)(b * 64 + n)) * DD);
                dst[lane * 2] = t0;
                dst[lane * 2 + 1] = t1;
            }
        }
    }
}

extern "C" void kernel_launch(void* const* d_in, const int* in_sizes, int n_in,
                              void* d_out, int out_size, void* d_ws, size_t ws_size,
                              hipStream_t stream) {
    const float* x       = (const float*)d_in[0];   // [8,1024,512]
    const float* tape0   = (const float*)d_in[1];   // [8,64,512]
    const float* hwork0  = (const float*)d_in[2];   // [8,512]
    const float* W_h     = (const float*)d_in[3];   // [512,512]
    const float* W_xz    = (const float*)d_in[4];   // [1024,512]
    const float* b_h     = (const float*)d_in[5];   // [512]
    const float* W_write = (const float*)d_in[6];   // [512,512]
    const float* g_z     = (const float*)d_in[7];
    const float* g_r     = (const float*)d_in[8];
    const float* g_h     = (const float*)d_in[9];
    const float* b_gate  = (const float*)d_in[10];

    float* out  = (float*)d_out;                        // outs [8,1024,512]
    float* tout = out + (size_t)8 * TT * DD;            // tape_final [8,64,512]

    char* ws = (char*)d_ws;
    u64* hbuf  = (u64*)ws;                              // [2][8][256] u64 = 32 KB
    u64* cbuf  = (u64*)(ws + 32768);                    // [2][8][8][256] u64 = 256 KB
    float* Zbuf = (float*)(ws + 327680);                // 16 MB

    (void)in_sizes; (void)n_in; (void)out_size; (void)ws_size;

    // 140,304 B dynamic LDS (> 64 KB default cap) — opt in every call (idempotent,
    // non-enqueuing; safe under graph capture).
    const int smem_bytes = (64 * PITCH + 3 * 512 + 4 * 64 + 128 + 2 * 64 + 4) * 4;
    hipFuncSetAttribute((const void*)rec_kernel,
                        hipFuncAttributeMaxDynamicSharedMemorySize, smem_bytes);

    dim3 pgrid(128, 16);
    proj_kernel<<<pgrid, 256, 0, stream>>>(x, W_xz, out, Zbuf);
    rec_kernel<<<64, 512, smem_bytes, stream>>>(tape0, hwork0, W_h, b_h, W_write,
                                                g_z, g_r, g_h, b_gate, Zbuf,
                                                out, tout, hbuf, cbuf);
}

// Round 6
// 4906.427 us; speedup vs baseline: 5.3941x; 2.1106x over previous
//
#include <hip/hip_runtime.h>
#include <math.h>

#define TT 1024
#define DD 512

typedef unsigned int u32;
typedef unsigned long long u64;
typedef _Float16 half2_t __attribute__((ext_vector_type(2)));

// ---------------- tagged cross-block atomics (agent scope, relaxed; R2-proven) ----
static __device__ __forceinline__ u64 aload64(const u64* p) {
    return __hip_atomic_load(p, __ATOMIC_RELAXED, __HIP_MEMORY_SCOPE_AGENT);
}
static __device__ __forceinline__ void astore64(u64* p, u64 v) {
    __hip_atomic_store(p, v, __ATOMIC_RELAXED, __HIP_MEMORY_SCOPE_AGENT);
}
static __device__ __forceinline__ u32 pkh2(float lo, float hi) {
    return __builtin_bit_cast(u32, __builtin_amdgcn_cvt_pkrtz(lo, hi));
}
static __device__ __forceinline__ float2 uph2(u32 v) {
    half2_t h = __builtin_bit_cast(half2_t, v);
    return make_float2((float)h.x, (float)h.y);
}
static __device__ __forceinline__ u64 mkword(u32 pay, u32 tag) {
    return ((u64)tag << 32) | (u64)pay;
}

static __device__ __forceinline__ float redux8(float v) {
    v += __shfl_xor(v, 1); v += __shfl_xor(v, 2); v += __shfl_xor(v, 4); return v;
}
static __device__ __forceinline__ float sum64(float v) {
    #pragma unroll
    for (int o = 32; o > 0; o >>= 1) v += __shfl_xor(v, o);
    return v;
}
static __device__ __forceinline__ float expc(float x) { return __expf(fminf(x, 60.f)); }
static __device__ __forceinline__ float fast_tanh(float x) {
    float xc = fminf(fmaxf(x, -15.f), 15.f);
    float e = __expf(2.f * xc);
    return (e - 1.f) / (e + 1.f);
}

// dot of 64 resident fp32 weights (16 float4) with 64 LDS floats (16B-aligned)
static __device__ __forceinline__ float dot64(const float4 (&w)[16], const float* hr) {
    float a0 = 0.f, a1 = 0.f, a2 = 0.f, a3 = 0.f;
    #pragma unroll
    for (int j = 0; j < 16; j += 4) {
        float4 h0 = *(const float4*)(hr + 4 * (j + 0));
        float4 h1 = *(const float4*)(hr + 4 * (j + 1));
        float4 h2 = *(const float4*)(hr + 4 * (j + 2));
        float4 h3 = *(const float4*)(hr + 4 * (j + 3));
        a0 += w[j + 0].x * h0.x + w[j + 0].y * h0.y + w[j + 0].z * h0.z + w[j + 0].w * h0.w;
        a1 += w[j + 1].x * h1.x + w[j + 1].y * h1.y + w[j + 1].z * h1.z + w[j + 1].w * h1.w;
        a2 += w[j + 2].x * h2.x + w[j + 2].y * h2.y + w[j + 2].z * h2.z + w[j + 2].w * h2.w;
        a3 += w[j + 3].x * h3.x + w[j + 3].y * h3.y + w[j + 3].z * h3.z + w[j + 3].w * h3.w;
    }
    return (a0 + a1) + (a2 + a3);
}

// ---------------- projection GEMM (unchanged) ----------------
__global__ __launch_bounds__(256) void proj_kernel(const float* __restrict__ x,
                                                   const float* __restrict__ Wxz,
                                                   float* __restrict__ xp,
                                                   float* __restrict__ z) {
    __shared__ float As[16][66];
    __shared__ float Bs[16][66];
    const int m0 = blockIdx.x * 64;
    const int n0 = blockIdx.y * 64;
    const int tid = threadIdx.x;
    const int tm = tid / 16, tn = tid % 16;
    float c[4][4] = {};
    for (int k0 = 0; k0 < 512; k0 += 16) {
        const int r = tid >> 2, c4 = (tid & 3) * 4;
        float4 a4 = *(const float4*)(x + (size_t)(m0 + r) * 512 + k0 + c4);
        float4 b4 = *(const float4*)(Wxz + (size_t)(n0 + r) * 512 + k0 + c4);
        As[c4 + 0][r] = a4.x; As[c4 + 1][r] = a4.y; As[c4 + 2][r] = a4.z; As[c4 + 3][r] = a4.w;
        Bs[c4 + 0][r] = b4.x; Bs[c4 + 1][r] = b4.y; Bs[c4 + 2][r] = b4.z; Bs[c4 + 3][r] = b4.w;
        __syncthreads();
        #pragma unroll
        for (int k = 0; k < 16; ++k) {
            float a0 = As[k][tm * 4 + 0], a1 = As[k][tm * 4 + 1];
            float a2 = As[k][tm * 4 + 2], a3 = As[k][tm * 4 + 3];
            float b0 = Bs[k][tn * 4 + 0], b1 = Bs[k][tn * 4 + 1];
            float b2 = Bs[k][tn * 4 + 2], b3 = Bs[k][tn * 4 + 3];
            c[0][0] += a0 * b0; c[0][1] += a0 * b1; c[0][2] += a0 * b2; c[0][3] += a0 * b3;
            c[1][0] += a1 * b0; c[1][1] += a1 * b1; c[1][2] += a1 * b2; c[1][3] += a1 * b3;
            c[2][0] += a2 * b0; c[2][1] += a2 * b1; c[2][2] += a2 * b2; c[2][3] += a2 * b3;
            c[3][0] += a3 * b0; c[3][1] += a3 * b1; c[3][2] += a3 * b2; c[3][3] += a3 * b3;
        }
        __syncthreads();
    }
    #pragma unroll
    for (int i = 0; i < 4; ++i) {
        const int m = m0 + tm * 4 + i;
        #pragma unroll
        for (int j = 0; j < 4; ++j) {
            const int e = n0 + tn * 4 + j;
            if (e < 512) xp[(size_t)m * 512 + e] = c[i][j];
            else         z[(size_t)m * 512 + (e - 512)] = c[i][j];
        }
    }
}

// ---------------- recurrence: 64 blocks = 8 batches x 8 d-chunks ----------------
// Dual-minimal design: block owns tape d-chunk tpd[64n][64d], W_h rows (chunk),
// W_write cols (chunk). Two hops/step, each gathered as EXACTLY 1 tagged u64 per
// thread. All score math d-chunk-partial; softmaxes recomputed per block.
__global__ __launch_bounds__(512) void rec_kernel(
    const float* __restrict__ tape0, const float* __restrict__ hwork0,
    const float* __restrict__ W_h, const float* __restrict__ b_h,
    const float* __restrict__ W_write,
    const float* __restrict__ g_z, const float* __restrict__ g_r,
    const float* __restrict__ g_h, const float* __restrict__ b_gate,
    const float* __restrict__ Zbuf,
    float* __restrict__ out, float* __restrict__ tape_out,
    u64* hA, u64* cA, u64* bB, u64* hB) {
    __shared__ float tpd[64][65];      // tape chunk [n][dd], pitch 65 (conflict-free both ways)
    __shared__ float hw2[8][68];       // full h(t-1), pitch 68 (conflict-free dot64)
    __shared__ float red[8][64];
    __shared__ float2 bred[8][64];     // hop-B combine
    __shared__ float2 cred[8][32];     // hop-A c combine
    __shared__ float wvc[64], rvc[64], hhc[64], hnc[64], xpc[64], zc[64], a_l[64], c1_l[64];
    __shared__ float hwv_s[8];
    __shared__ float c2_s;

    const int b = blockIdx.x & 7, s = blockIdx.x >> 3;   // batch -> XCD, chunk
    const int tid = threadIdx.x, lane = tid & 63, wid = tid >> 6;
    const int n8 = tid >> 3, l = tid & 7;
    const int d0 = s * 64;
    const float scale = 0.044194173824159216f;  // 1/sqrt(512)

    // --- resident weights (128 VGPRs total) ---
    float4 wh[16];    // W_h[d0+n8][l*64 + 4j..]
    float4 wwc[16];   // W_write[tid][d0 + 4j..]   (column slice for c_j)
    {
        const float4* w1 = (const float4*)(W_h + (size_t)(d0 + n8) * DD + l * 64);
        #pragma unroll
        for (int j = 0; j < 16; ++j) wh[j] = w1[j];
        const float4* w2 = (const float4*)(W_write + (size_t)tid * DD + d0);
        #pragma unroll
        for (int j = 0; j < 16; ++j) wwc[j] = w2[j];
    }
    float bhr = 0.f, gz = 0.f, gr = 0.f, gh = 0.f, bg = 0.f;
    if (wid == 0) bhr = b_h[d0 + lane];
    if (wid == 1) { gz = g_z[d0 + lane]; gr = g_r[d0 + lane]; gh = g_h[d0 + lane]; bg = b_gate[d0 + lane]; }

    // --- init LDS ---
    {   // tpd chunk: thread (n=tid>>3, c0=(tid&7)*8) loads 8 floats
        const int n = tid >> 3, c0 = (tid & 7) * 8;
        const float* src = tape0 + ((size_t)(b * 64 + n)) * DD + d0 + c0;
        #pragma unroll
        for (int i = 0; i < 8; ++i) tpd[n][c0 + i] = src[i];
    }
    hw2[tid >> 6][tid & 63] = hwork0[(size_t)b * DD + tid];
    if (tid < 64) { wvc[tid] = 0.f; a_l[tid] = 0.f; }
    if (tid == 0) c2_s = 0.f;
    __syncthreads();

    // --- bootstrap hop B: q0(n) partials from h(-1), tag 0, parity 1 ---
    {
        float pq = 0.f;
        #pragma unroll
        for (int i = 0; i < 8; ++i) pq += hw2[s][l * 8 + i] * tpd[n8][l * 8 + i];
        pq = redux8(pq);
        if (l == 0)
            astore64(&bB[(((size_t)1 * 8 + b) * 8 + s) * 64 + n8], mkword(pkh2(0.f, pq), 0u));
    }
    {
        const int n = tid & 63, j = tid >> 6;
        const u64* p = &bB[(((size_t)1 * 8 + b) * 8 + j) * 64 + n];
        u64 v;
        for (;;) { v = aload64(p); if ((u32)(v >> 32) == 0u) break; __builtin_amdgcn_s_sleep(1); }
        bred[j][n] = uph2((u32)v);
    }
    __syncthreads();
    if (wid == 0) {
        float q0 = 0.f;
        #pragma unroll
        for (int j = 0; j < 8; ++j) q0 += bred[j][lane].y;
        float er = expc(scale * q0);
        float Zr = sum64(er);
        c1_l[lane] = __fdividef(er, Zr);   // c1 = r (a=0)
    }
    __syncthreads();

    // ---------------- main scan ----------------
    for (int t = 0; t < TT; ++t) {
        const int pA = t & 1, pB = t & 1;
        const u32 tg = (u32)(t + 1);

        // P0: prefetch xp/z(t) into regs (waves 2,3)
        float xpr = 0.f, zr = 0.f;
        if (wid == 2)      xpr = out[((size_t)(b * TT + t)) * DD + d0 + lane];
        else if (wid == 3) zr  = Zbuf[((size_t)(b * TT + t)) * DD + d0 + lane];

        // P1a: hh = (W_h . h(t-1))[chunk]
        {
            float acc = dot64(wh, &hw2[l][0]);
            acc = redux8(acc);
            if (l == 0) hhc[n8] = acc;
        }
        // P1b: fused rv-partials (c1, over OLD tape) + tape lerp (a(t-1), wv(t-1))
        {
            float acc = 0.f;
            const float wvd = wvc[lane];
            #pragma unroll
            for (int k = 0; k < 8; ++k) {
                const int n = wid * 8 + k;
                float tp = tpd[n][lane];
                acc += c1_l[n] * tp;
                tpd[n][lane] = tp + a_l[n] * (wvd - tp);
            }
            red[wid][lane] = acc;
        }
        if (wid == 2)      xpc[lane] = xpr;
        else if (wid == 3) zc[lane] = zr;
        __syncthreads();                                   // B1
        // P2: rv + h(t) chunk (wave0)
        if (wid == 0) {
            float acc = c2_s * wvc[lane];
            #pragma unroll
            for (int g = 0; g < 8; ++g) acc += red[g][lane];
            rvc[lane] = acc;
            hnc[lane] = fast_tanh(xpc[lane] + hhc[lane] + acc + bhr);
        }
        __syncthreads();                                   // B2
        // P3: out(t) epilogue (wave1)
        if (wid == 1) {
            float h = hnc[lane];
            float g = zc[lane] * gz + rvc[lane] * gr + h * gh + bg;
            g = fminf(fmaxf(g, -20.f), 20.f);
            float sig = 1.f / (1.f + __expf(-g));
            out[((size_t)(b * TT + t)) * DD + d0 + lane] = h * g * sig;
        }
        // P4a: publish h chunk (wave0, even lanes)
        if (wid == 0 && (lane & 1) == 0)
            astore64(&hA[((size_t)pA * 8 + b) * 256 + s * 32 + (lane >> 1)],
                     mkword(pkh2(hnc[lane], hnc[lane + 1]), tg));
        // P4b: c_j = W_write[:,chunk] . h_chunk, publish (all threads; pairs)
        {
            float cj = 0.f;
            #pragma unroll
            for (int j = 0; j < 16; ++j) {
                float4 h4 = *(const float4*)&hnc[4 * j];
                cj += wwc[j].x * h4.x + wwc[j].y * h4.y + wwc[j].z * h4.z + wwc[j].w * h4.w;
            }
            float cn = __shfl_xor(cj, 1);
            if ((tid & 1) == 0)
                astore64(&cA[(((size_t)pA * 8 + b) * 8 + s) * 256 + (tid >> 1)],
                         mkword(pkh2(cj, cn), tg));
        }
        // P5: poll hop A — exactly 1 word per thread
        if (tid < 256) {
            const u64* p = &hA[((size_t)pA * 8 + b) * 256 + tid];
            u64 v;
            for (;;) { v = aload64(p); if ((u32)(v >> 32) == tg) break; __builtin_amdgcn_s_sleep(1); }
            float2 hp = uph2((u32)v);
            hw2[tid >> 5][2 * (tid & 31)] = hp.x;
            hw2[tid >> 5][2 * (tid & 31) + 1] = hp.y;
        } else {
            const int k = tid - 256, j = k >> 5, w = k & 31;
            const u64* p = &cA[(((size_t)pA * 8 + b) * 8 + j) * 256 + s * 32 + w];
            u64 v;
            for (;;) { v = aload64(p); if ((u32)(v >> 32) == tg) break; __builtin_amdgcn_s_sleep(1); }
            cred[j][w] = uph2((u32)v);
        }
        __syncthreads();                                   // B3
        // P6: wv chunk = sum of 8 c_j chunks (wave0, lanes<32)
        if (wid == 0 && lane < 32) {
            float lo = 0.f, hi = 0.f;
            #pragma unroll
            for (int j = 0; j < 8; ++j) { float2 c = cred[j][lane]; lo += c.x; hi += c.y; }
            wvc[2 * lane] = lo; wvc[2 * lane + 1] = hi;
        }
        __syncthreads();                                   // B4
        // P7a: score partials vs NEW tape (post-write t-1) + publish
        {
            float pw = 0.f, pq = 0.f;
            #pragma unroll
            for (int i = 0; i < 8; ++i) {
                float tp = tpd[n8][l * 8 + i];
                pw += wvc[l * 8 + i] * tp;
                pq += hnc[l * 8 + i] * tp;
            }
            pw = redux8(pw); pq = redux8(pq);
            if (l == 0)
                astore64(&bB[(((size_t)pB * 8 + b) * 8 + s) * 64 + n8],
                         mkword(pkh2(pw, pq), tg));
        }
        // P7b: hwv partial (wave1)
        if (wid == 1) {
            float hv = sum64(hnc[lane] * wvc[lane]);
            if (lane == 0) astore64(&hB[((size_t)pB * 8 + b) * 8 + s], mkword(pkh2(hv, 0.f), tg));
        }
        // P8: poll hop B — 1 word per thread (+8 threads take the hwv words)
        {
            const int n = tid & 63, j = tid >> 6;
            const u64* p = &bB[(((size_t)pB * 8 + b) * 8 + j) * 64 + n];
            u64 v;
            for (;;) { v = aload64(p); if ((u32)(v >> 32) == tg) break; __builtin_amdgcn_s_sleep(1); }
            bred[j][n] = uph2((u32)v);
        }
        if (tid < 8) {
            const u64* p = &hB[((size_t)pB * 8 + b) * 8 + tid];
            u64 v;
            for (;;) { v = aload64(p); if ((u32)(v >> 32) == tg) break; __builtin_amdgcn_s_sleep(1); }
            hwv_s[tid] = uph2((u32)v).x;
        }
        __syncthreads();                                   // B5
        // P9: reduce + softmaxes (wave0), fused next-read-score
        if (wid == 0) {
            float ws = 0.f, q0 = 0.f;
            #pragma unroll
            for (int j = 0; j < 8; ++j) { float2 v = bred[j][lane]; ws += v.x; q0 += v.y; }
            float hv = 0.f;
            #pragma unroll
            for (int j = 0; j < 8; ++j) hv += hwv_s[j];
            float ew = expc(scale * ws);
            float Zw = sum64(ew);
            float a = __fdividef(ew, Zw);
            float er = expc(scale * ((1.f - a) * q0 + a * hv));
            float Zr = sum64(er);
            float r = __fdividef(er, Zr);
            a_l[lane] = a;
            c1_l[lane] = r * (1.f - a);
            float c2 = sum64(r * a);
            if (lane == 0) c2_s = c2;
        }
        __syncthreads();                                   // B6
    }

    // ---- epilogue: final lerp (a(T-1), wv(T-1)) + write tape chunk ----
    {
        const int n = tid >> 3, c0 = (tid & 7) * 8;
        const float an = a_l[n];
        float* dst = tape_out + ((size_t)(b * 64 + n)) * DD + d0 + c0;
        #pragma unroll
        for (int i = 0; i < 8; ++i) {
            float tp = tpd[n][c0 + i];
            tp += an * (wvc[c0 + i] - tp);
            dst[i] = tp;
        }
    }
}

extern "C" void kernel_launch(void* const* d_in, const int* in_sizes, int n_in,
                              void* d_out, int out_size, void* d_ws, size_t ws_size,
                              hipStream_t stream) {
    const float* x       = (const float*)d_in[0];   // [8,1024,512]
    const float* tape0   = (const float*)d_in[1];   // [8,64,512]
    const float* hwork0  = (const float*)d_in[2];   // [8,512]
    const float* W_h     = (const float*)d_in[3];   // [512,512]
    const float* W_xz    = (const float*)d_in[4];   // [1024,512]
    const float* b_h     = (const float*)d_in[5];   // [512]
    const float* W_write = (const float*)d_in[6];   // [512,512]
    const float* g_z     = (const float*)d_in[7];
    const float* g_r     = (const float*)d_in[8];
    const float* g_h     = (const float*)d_in[9];
    const float* b_gate  = (const float*)d_in[10];

    float* out  = (float*)d_out;                        // outs [8,1024,512]
    float* tout = out + (size_t)8 * TT * DD;            // tape_final [8,64,512]

    char* ws = (char*)d_ws;
    u64* hA   = (u64*)ws;                               // [2][8][256]      = 32 KB
    u64* cA   = (u64*)(ws + 32768);                     // [2][8][8][256]   = 256 KB
    u64* bB   = (u64*)(ws + 294912);                    // [2][8][8][64]    = 64 KB
    u64* hB   = (u64*)(ws + 360448);                    // [2][8][8]        = 1 KB
    float* Zbuf = (float*)(ws + 393216);                // 16 MB

    (void)in_sizes; (void)n_in; (void)out_size; (void)ws_size;

    // tags equality-checked against monotone values; 0xAA poison never matches.
    dim3 pgrid(128, 16);
    proj_kernel<<<pgrid, 256, 0, stream>>>(x, W_xz, out, Zbuf);
    rec_kernel<<<64, 512, 0, stream>>>(tape0, hwork0, W_h, b_h, W_write,
                                       g_z, g_r, g_h, b_gate, Zbuf,
                                       out, tout, hA, cA, bB, hB);
}